// Round 15
// baseline (66.023 us; speedup 1.0000x reference)
//
#include <hip/hip_runtime.h>
#include <stdint.h>

#define N 1024
#define DD 256
#define EPS 100.0f
#define INV_EPS 0.01f
#define LOG_MU -6.93147180559945f

__device__ __forceinline__ float waveReduceSum(float s) {
#pragma unroll
  for (int m = 1; m <= 32; m <<= 1) s += __shfl_xor(s, m);
  return s;
}

// Relaxed agent-scope 64-bit accesses (cache-bypassing, no cache maintenance).
__device__ __forceinline__ uint64_t rload64(const uint64_t* p) {
  return __hip_atomic_load(p, __ATOMIC_RELAXED, __HIP_MEMORY_SCOPE_AGENT);
}
__device__ __forceinline__ void rstore64(uint64_t* p, uint64_t x) {
  __hip_atomic_store(p, x, __ATOMIC_RELAXED, __HIP_MEMORY_SCOPE_AGENT);
}
__device__ __forceinline__ uint64_t packtag(uint32_t tag, float val) {
  return ((uint64_t)tag << 32) | (uint64_t)__float_as_uint(val);
}

// Poll 4 tagged words (thread t owns slots t*4..t*4+3); payload already in
// exp-domain -> post-poll work is a pure copy. All-or-nothing reload keeps
// the 4 loads pipelined.
__device__ __forceinline__ void stage_cp(const uint64_t* __restrict__ src,
                                         uint32_t want, float* sB, int t) {
  const int base = t * 4;
  for (;;) {
    const uint64_t a0 = rload64(src + base + 0);
    const uint64_t a1 = rload64(src + base + 1);
    const uint64_t a2 = rload64(src + base + 2);
    const uint64_t a3 = rload64(src + base + 3);
    if ((uint32_t)(a0 >> 32) == want && (uint32_t)(a1 >> 32) == want &&
        (uint32_t)(a2 >> 32) == want && (uint32_t)(a3 >> 32) == want) {
      sB[base + 0] = __uint_as_float((uint32_t)a0);
      sB[base + 1] = __uint_as_float((uint32_t)a1);
      sB[base + 2] = __uint_as_float((uint32_t)a2);
      sB[base + 3] = __uint_as_float((uint32_t)a3);
      return;
    }
    __builtin_amdgcn_s_sleep(1);
  }
}

#define NTAGS 6160  // U(2048) V(2048) DERR(1024) PART(1024) DONE(16)
#define XS_H 4352   // 64*68 floats per half
#define YS_H 4096   // 64*64 floats per half (XOR-swizzled)

// ---- cmat: K=exp(-|x-y|_1/eps) and KT; zeroes tag words each call ----
// 64x64 tile, 512 threads, grid (16,16)=256 blocks (1/CU, 8 waves/CU).
// k-SPLIT: waves 0-3 accumulate k in [0,128), waves 4-7 k in [128,256),
// each half in its own LDS buffers -> 4x4 register blocking (537 MB total
// LDS compute-read traffic, the minimum at this occupancy) AND 8 waves/CU.
// Halves combined via LDS in the epilogue (no global handshake).
__global__ __launch_bounds__(512) void cmat_kernel(
    const float* __restrict__ x, const float* __restrict__ y,
    float* __restrict__ Km, float* __restrict__ KTm,
    uint64_t* __restrict__ tags) {
  __shared__ float lds[2 * XS_H + 2 * YS_H];  // 67.6 KB
  const int tid = threadIdx.x;
  const int h = tid >> 8;  // k-half (wave-uniform)
  const int t = tid & 255;
  const int bj = blockIdx.x;  // 64-col tile
  const int bi = blockIdx.y;  // 64-row tile
  if (bi == 0 && bj == 0) {   // coop runs strictly after in stream order
    for (int z = tid; z < NTAGS; z += 512) tags[z] = 0;
  }
  float* xsh = lds + h * XS_H;
  float* ysh = lds + 2 * XS_H + h * YS_H;
  const int tx = t & 15, ty = t >> 4;
  const int r0 = ty * 4, c0 = tx * 4;
  const int ysw = (tx & 7) << 2;  // uniform read swizzle
  const float* xg = x + (size_t)(bi * 64) * DD + h * 128;
  const float* yg = y + (size_t)(bj * 64) * DD + h * 128;

  float acc[4][4] = {};
  float4 gx[4], gy[4];
#pragma unroll
  for (int it = 0; it < 4; ++it) {  // preload chunk 0 of my half
    const int l = it * 256 + t;
    const int row = l >> 4, kq = l & 15;
    gx[it] = *reinterpret_cast<const float4*>(xg + row * DD + kq * 4);
    gy[it] = *reinterpret_cast<const float4*>(yg + row * DD + kq * 4);
  }
  for (int kc = 0; kc < 128; kc += 64) {
    __syncthreads();
#pragma unroll
    for (int it = 0; it < 4; ++it) {  // regs -> LDS (ys XOR-swizzled)
      const int l = it * 256 + t;
      const int row = l >> 4, kq = l & 15;
      *reinterpret_cast<float4*>(&xsh[row * 68 + kq * 4]) = gx[it];
      const int col16 = kq ^ ((row >> 2) & 7);
      *reinterpret_cast<float4*>(&ysh[row * 64 + col16 * 4]) = gy[it];
    }
    __syncthreads();
    if (kc == 0) {  // prefetch chunk 1 (latency hidden under compute)
#pragma unroll
      for (int it = 0; it < 4; ++it) {
        const int l = it * 256 + t;
        const int row = l >> 4, kq = l & 15;
        gx[it] =
            *reinterpret_cast<const float4*>(xg + row * DD + 64 + kq * 4);
        gy[it] =
            *reinterpret_cast<const float4*>(yg + row * DD + 64 + kq * 4);
      }
    }
#pragma unroll 4
    for (int kk = 0; kk < 64; kk += 4) {
      float4 xr[4], yc[4];
#pragma unroll
      for (int rr = 0; rr < 4; ++rr)
        xr[rr] = *reinterpret_cast<const float4*>(&xsh[(r0 + rr) * 68 + kk]);
#pragma unroll
      for (int cc = 0; cc < 4; ++cc)
        yc[cc] = *reinterpret_cast<const float4*>(
            &ysh[(c0 + cc) * 64 + (kk ^ ysw)]);
#pragma unroll
      for (int rr = 0; rr < 4; ++rr)
#pragma unroll
        for (int cc = 0; cc < 4; ++cc)
          acc[rr][cc] += fabsf(xr[rr].x - yc[cc].x) +
                         fabsf(xr[rr].y - yc[cc].y) +
                         fabsf(xr[rr].z - yc[cc].z) +
                         fabsf(xr[rr].w - yc[cc].w);
    }
  }
  // ---- combine halves via LDS; half 0 finishes exp + stores ----
  float* part = lds;           // alias half-0 xs region (16 KB needed)
  float* trans = lds + XS_H;   // alias half-1 xs region (64x68)
  __syncthreads();             // all compute reads done
  if (h == 1) {
#pragma unroll
    for (int rr = 0; rr < 4; ++rr)
      *reinterpret_cast<float4*>(&part[t * 16 + rr * 4]) =
          make_float4(acc[rr][0], acc[rr][1], acc[rr][2], acc[rr][3]);
  }
  __syncthreads();
  if (h == 0) {
    float kv[4][4];
#pragma unroll
    for (int rr = 0; rr < 4; ++rr) {
      const float4 p = *reinterpret_cast<const float4*>(&part[t * 16 + rr * 4]);
      kv[rr][0] = expf(-(acc[rr][0] + p.x) * INV_EPS);
      kv[rr][1] = expf(-(acc[rr][1] + p.y) * INV_EPS);
      kv[rr][2] = expf(-(acc[rr][2] + p.z) * INV_EPS);
      kv[rr][3] = expf(-(acc[rr][3] + p.w) * INV_EPS);
    }
    const int gr0 = bi * 64 + r0;
    const int gc0 = bj * 64 + c0;
#pragma unroll
    for (int rr = 0; rr < 4; ++rr)
      *reinterpret_cast<float4*>(Km + (size_t)(gr0 + rr) * N + gc0) =
          make_float4(kv[rr][0], kv[rr][1], kv[rr][2], kv[rr][3]);
#pragma unroll
    for (int rr = 0; rr < 4; ++rr)
#pragma unroll
      for (int cc = 0; cc < 4; ++cc)
        trans[(c0 + cc) * 68 + r0 + rr] = kv[rr][cc];
  }
  __syncthreads();
#pragma unroll
  for (int it = 0; it < 2; ++it) {  // KT store, all 512 threads
    const int l = it * 512 + tid;   // 1024 float4s
    const int crow = l >> 4, cq = l & 15;
    const float4 val =
        *reinterpret_cast<const float4*>(&trans[crow * 68 + cq * 4]);
    *reinterpret_cast<float4*>(KTm + (size_t)(bj * 64 + crow) * N + bi * 64 +
                               cq * 4) = val;
  }
}

// ---- persistent Sinkhorn: tagged dataflow + off-path aggregator (R14) ----
__global__ __launch_bounds__(256, 1) void sinkhorn_coop(
    const float* __restrict__ Km, const float* __restrict__ KTm,
    uint64_t* __restrict__ U, uint64_t* __restrict__ V,
    uint64_t* __restrict__ DERR, uint64_t* __restrict__ PART,
    uint64_t* __restrict__ DONE, float* __restrict__ out) {
  const int b = blockIdx.x, t = threadIdx.x;
  const int lane = t & 63, w = t >> 6;

  if (b == 256) {  // ---- aggregator block (wave 0 only) ----
    if (w != 0) return;
    for (int it = 0; it < 9; ++it) {
      const uint32_t k = it + 1;
      float e = 0.f;
#pragma unroll
      for (int q = 0; q < 16; ++q) {
        const int idx = q * 64 + lane;
        uint64_t d;
        while ((uint32_t)((d = rload64(DERR + idx)) >> 32) != k)
          __builtin_amdgcn_s_sleep(1);
        e += __uint_as_float((uint32_t)d);
      }
      e = waveReduceSum(e);
      if (lane == 0)
        rstore64(DONE + it, ((uint64_t)k << 32) | (e < 0.1f ? 1u : 0u));
      if (__shfl(e, 0) < 0.1f) return;  // later DERR tags never arrive
    }
    return;
  }

  __shared__ float Ksh[4][N];  // my 4 K rows (row pass)
  __shared__ float Tsh[4][N];  // my 4 KT rows (col pass)
  __shared__ float sB[N];
  __shared__ float sRed[4];
  __shared__ int sDone;
  const int i = b * 4 + w;

  // ---- prologue: K/KT rows -> LDS (L2-hot after cmat) ----
#pragma unroll
  for (int q = 0; q < 4; ++q) {
    const int idx = q * 256 + t;  // 1024 float4s per matrix
    const int rr = idx >> 8, cc = idx & 255;
    *reinterpret_cast<float4*>(&Ksh[rr][cc * 4]) =
        *reinterpret_cast<const float4*>(Km + (size_t)(b * 4 + rr) * N +
                                         cc * 4);
    *reinterpret_cast<float4*>(&Tsh[rr][cc * 4]) =
        *reinterpret_cast<const float4*>(KTm + (size_t)(b * 4 + rr) * N +
                                         cc * 4);
  }
  __syncthreads();

  float ui = 0.f, vj = 0.f;
  int klast = 0;

  for (int it = 0; it < 10; ++it) {
    const uint32_t k = it + 1;
    // ---- stage b_j = exp(v^{k-1}_j/eps) (exp-domain payload); it0 -> 1 ----
    if (it == 0) {
      *reinterpret_cast<float4*>(&sB[t * 4]) = make_float4(1.f, 1.f, 1.f, 1.f);
    } else {
      stage_cp(V + (size_t)((k - 1) & 1) * N, k - 1, sB, t);
    }
    __syncthreads();
    // ---- row pass: S = sum_j K_ij b_j ; u update; publish U(exp), DERR ----
    {
      float s = 0.f;
#pragma unroll
      for (int q = 0; q < 4; ++q) {
        const int j4 = (q * 64 + lane) * 4;
        const float4 k4 = *reinterpret_cast<const float4*>(&Ksh[w][j4]);
        s += k4.x * sB[j4] + k4.y * sB[j4 + 1] + k4.z * sB[j4 + 2] +
             k4.w * sB[j4 + 3];
      }
      s = waveReduceSum(s);
      const float un =
          EPS * (LOG_MU - logf(expf(ui * INV_EPS) * s + 1e-6f)) + ui;
      const float de = fabsf(un - ui);
      ui = un;
      if (lane == 0) {
        rstore64(U + (size_t)(k & 1) * N + i, packtag(k, expf(ui * INV_EPS)));
        if (it < 9) rstore64(DERR + i, packtag(k, de));
      }
    }
    __syncthreads();  // all waves done reading sB before restage
    // ---- stage a_i = exp(u^k_i/eps) ----
    stage_cp(U + (size_t)(k & 1) * N, k, sB, t);
    __syncthreads();
    // ---- col pass: v update; iteration 10 fuses the loss ----
    if (it < 9) {
      float s = 0.f;
#pragma unroll
      for (int q = 0; q < 4; ++q) {
        const int i4 = (q * 64 + lane) * 4;
        const float4 k4 = *reinterpret_cast<const float4*>(&Tsh[w][i4]);
        s += k4.x * sB[i4] + k4.y * sB[i4 + 1] + k4.z * sB[i4 + 2] +
             k4.w * sB[i4 + 3];
      }
      s = waveReduceSum(s);
      vj = EPS * (LOG_MU - logf(expf(vj * INV_EPS) * s + 1e-6f)) + vj;
      if (lane == 0)
        rstore64(V + (size_t)(k & 1) * N + i, packtag(k, expf(vj * INV_EPS)));
      klast = (int)k;
      // ---- DONE poll (aggregator published it during our col pass) ----
      if (t == 0) {
        uint64_t d;
        while ((uint32_t)((d = rload64(DONE + it)) >> 32) != k)
          __builtin_amdgcn_s_sleep(1);
        sDone = (int)(d & 1);
      }
      __syncthreads();  // also guards sB restage of next iteration
      if (sDone) break;
    } else {
      // last col pass: s = sum KT*a ; sl = sum KT*a*C, C = -eps*ln(KT)
      float s = 0.f, sl = 0.f;
#pragma unroll
      for (int q = 0; q < 4; ++q) {
        const int i4 = (q * 64 + lane) * 4;
        const float4 k4 = *reinterpret_cast<const float4*>(&Tsh[w][i4]);
        const float p0 = k4.x * sB[i4], p1 = k4.y * sB[i4 + 1],
                    p2 = k4.z * sB[i4 + 2], p3 = k4.w * sB[i4 + 3];
        s += p0 + p1 + p2 + p3;
        sl += p0 * logf(k4.x) + p1 * logf(k4.y) + p2 * logf(k4.z) +
              p3 * logf(k4.w);
      }
      s = waveReduceSum(s);
      sl = waveReduceSum(sl) * -EPS;
      vj = EPS * (LOG_MU - logf(expf(vj * INV_EPS) * s + 1e-6f)) + vj;
      if (lane == 0) rstore64(PART + i, packtag(1u, expf(vj * INV_EPS) * sl));
      klast = 10;
    }
  }
  // ---- early-exit loss path (statically unreachable for this input) ----
  if (klast < 10) {
    stage_cp(V + (size_t)(klast & 1) * N, (uint32_t)klast, sB, t);
    __syncthreads();
    float sl = 0.f;
#pragma unroll
    for (int q = 0; q < 4; ++q) {
      const int j4 = (q * 64 + lane) * 4;
      const float4 k4 = *reinterpret_cast<const float4*>(&Ksh[w][j4]);
      sl += (k4.x * sB[j4]) * logf(k4.x) + (k4.y * sB[j4 + 1]) * logf(k4.y) +
            (k4.z * sB[j4 + 2]) * logf(k4.z) +
            (k4.w * sB[j4 + 3]) * logf(k4.w);
    }
    sl = waveReduceSum(sl) * -EPS;
    if (lane == 0) rstore64(PART + i, packtag(1u, expf(ui * INV_EPS) * sl));
  }
  // ---- final reduce: block 0 polls 1024 partials, fixed-order tree ----
  if (b == 0) {
    float acc = 0.f;
#pragma unroll
    for (int q = 0; q < 4; ++q) {
      const int idx = t * 4 + q;
      uint64_t d;
      while ((uint32_t)((d = rload64(PART + idx)) >> 32) != 1u)
        __builtin_amdgcn_s_sleep(1);
      acc += __uint_as_float((uint32_t)d);
    }
    acc = waveReduceSum(acc);
    if (lane == 0) sRed[w] = acc;
    __syncthreads();
    if (t == 0) out[0] = sRed[0] + sRed[1] + sRed[2] + sRed[3];
  }
}

extern "C" void kernel_launch(void* const* d_in, const int* in_sizes, int n_in,
                              void* d_out, int out_size, void* d_ws,
                              size_t ws_size, hipStream_t stream) {
  const float* x = (const float*)d_in[0];  // "output"
  const float* y = (const float*)d_in[1];  // "target"
  float* out = (float*)d_out;

  const size_t nn = (size_t)N * N;
  float* Km = (float*)d_ws;
  float* KTm = Km + nn;
  uint64_t* tags = (uint64_t*)(KTm + nn);
  uint64_t* U = tags;          // 2*N
  uint64_t* V = U + 2 * N;     // 2*N
  uint64_t* DERR = V + 2 * N;  // N
  uint64_t* PART = DERR + N;   // N
  uint64_t* DONE = PART + N;   // 16

  cmat_kernel<<<dim3(16, 16), 512, 0, stream>>>(x, y, Km, KTm, tags);
  sinkhorn_coop<<<257, 256, 0, stream>>>(Km, KTm, U, V, DERR, PART, DONE, out);
}

// Round 16
// 58.998 us; speedup vs baseline: 1.1191x; 1.1191x over previous
//
#include <hip/hip_runtime.h>
#include <stdint.h>

#define N 1024
#define DD 256
#define EPS 100.0f
#define INV_EPS 0.01f
#define LOG_MU -6.93147180559945f

__device__ __forceinline__ float waveReduceSum(float s) {
#pragma unroll
  for (int m = 1; m <= 32; m <<= 1) s += __shfl_xor(s, m);
  return s;
}

// Relaxed agent-scope 64-bit accesses (cache-bypassing, no cache maintenance).
__device__ __forceinline__ uint64_t rload64(const uint64_t* p) {
  return __hip_atomic_load(p, __ATOMIC_RELAXED, __HIP_MEMORY_SCOPE_AGENT);
}
__device__ __forceinline__ void rstore64(uint64_t* p, uint64_t x) {
  __hip_atomic_store(p, x, __ATOMIC_RELAXED, __HIP_MEMORY_SCOPE_AGENT);
}
__device__ __forceinline__ uint64_t packtag(uint32_t tag, float val) {
  return ((uint64_t)tag << 32) | (uint64_t)__float_as_uint(val);
}

// Poll 4 tagged words (thread t owns slots t*4..t*4+3), write exp(val/eps)
// into sB. All-or-nothing reload keeps the 4 loads pipelined. (R11-exact.)
__device__ __forceinline__ void stage_exp(const uint64_t* __restrict__ src,
                                          uint32_t want, float* sB, int t) {
  const int base = t * 4;
  for (;;) {
    const uint64_t a0 = rload64(src + base + 0);
    const uint64_t a1 = rload64(src + base + 1);
    const uint64_t a2 = rload64(src + base + 2);
    const uint64_t a3 = rload64(src + base + 3);
    if ((uint32_t)(a0 >> 32) == want && (uint32_t)(a1 >> 32) == want &&
        (uint32_t)(a2 >> 32) == want && (uint32_t)(a3 >> 32) == want) {
      sB[base + 0] = expf(__uint_as_float((uint32_t)a0) * INV_EPS);
      sB[base + 1] = expf(__uint_as_float((uint32_t)a1) * INV_EPS);
      sB[base + 2] = expf(__uint_as_float((uint32_t)a2) * INV_EPS);
      sB[base + 3] = expf(__uint_as_float((uint32_t)a3) * INV_EPS);
      return;
    }
    __builtin_amdgcn_s_sleep(1);
  }
}

#define NTAGS 6160  // U(2048) V(2048) DERR(1024) PART(1024) DONE(16)

typedef __attribute__((address_space(3))) uint32_t lds_u32_t;
typedef __attribute__((address_space(1))) const uint32_t glb_u32_t;
__device__ __forceinline__ void gload_lds16(const float* g, float* l) {
  __builtin_amdgcn_global_load_lds((glb_u32_t*)g, (lds_u32_t*)l, 16, 0, 0);
}

// ---- cmat: K=exp(-|x-y|_1/eps) and KT; zeroes tag words each call ----
// 64x32 tile, grid (32,16)=512 blocks (2/CU), 4x2 acc (R11 config), but
// staging via global_load_lds (width 16) + DOUBLE-BUFFERED LDS: chunk k+1's
// loads are issued straight to the idle buffer before computing chunk k, so
// global latency hides under compute and the VGPR round-trip is gone.
// global_load_lds writes linearly (wave-uniform base + lane*16), so LDS is
// unpadded and bank conflicts are avoided by PRE-SWIZZLING THE GLOBAL SOURCE:
// slot (row, c16) holds global granule c16 ^ ((row>>2)&7); compute reads use
// the matching uniform per-thread XOR. xs reads: 16-lane broadcast per row
// group, conflict-free. ys reads: 2-way aliasing (free, m136).
__global__ __launch_bounds__(256) void cmat_kernel(
    const float* __restrict__ x, const float* __restrict__ y,
    float* __restrict__ Km, float* __restrict__ KTm,
    uint64_t* __restrict__ tags) {
  __shared__ float xsA[64 * 64], xsB[64 * 64];  // 16 KB each
  __shared__ float ysA[32 * 64], ysB[32 * 64];  // 8 KB each
  const int t = threadIdx.x;
  const int bj = blockIdx.x;  // 32-col tile
  const int bi = blockIdx.y;  // 64-row tile
  if (bi == 0 && bj == 0) {   // coop runs strictly after in stream order
    for (int z = t; z < NTAGS; z += 256) tags[z] = 0;
  }
  const int tx = t & 15;
  const int ty = t >> 4;
  const int c0 = tx * 2, c1 = c0 + 1;
  const int xsw = (ty & 7) << 2;         // read swizzle: ((ty*4+r)>>2)&7 = ty
  const int ysw = ((tx >> 1) & 7) << 2;  // ((2tx)>>2)&7 == ((2tx+1)>>2)&7
  const float* xg = x + (size_t)(bi * 64) * DD;
  const float* yg = y + (size_t)(bj * 32) * DD;

  float acc[4][2] = {};

  auto issue = [&](float* xs, float* ys, int kc) {
#pragma unroll
    for (int q = 0; q < 4; ++q) {  // xs: 1024 slots (64 rows x 16 granules)
      const int s = q * 256 + t;
      const int row = s >> 4, c16 = s & 15;
      const int g16 = c16 ^ ((row >> 2) & 7);  // pre-swizzled source granule
      gload_lds16(xg + (size_t)row * DD + kc + g16 * 4, xs + s * 4);
    }
#pragma unroll
    for (int q = 0; q < 2; ++q) {  // ys: 512 slots (32 rows x 16 granules)
      const int s = q * 256 + t;
      const int row = s >> 4, c16 = s & 15;
      const int g16 = c16 ^ ((row >> 2) & 7);
      gload_lds16(yg + (size_t)row * DD + kc + g16 * 4, ys + s * 4);
    }
  };

  auto compute = [&](const float* xs, const float* ys) {
#pragma unroll 2
    for (int kk = 0; kk < 64; kk += 4) {
      float4 xr[4];
#pragma unroll
      for (int r = 0; r < 4; ++r)
        xr[r] = *reinterpret_cast<const float4*>(
            &xs[(ty * 4 + r) * 64 + (kk ^ xsw)]);
      const float4 ya =
          *reinterpret_cast<const float4*>(&ys[c0 * 64 + (kk ^ ysw)]);
      const float4 yb =
          *reinterpret_cast<const float4*>(&ys[c1 * 64 + (kk ^ ysw)]);
#pragma unroll
      for (int r = 0; r < 4; ++r) {
        acc[r][0] += fabsf(xr[r].x - ya.x) + fabsf(xr[r].y - ya.y) +
                     fabsf(xr[r].z - ya.z) + fabsf(xr[r].w - ya.w);
        acc[r][1] += fabsf(xr[r].x - yb.x) + fabsf(xr[r].y - yb.y) +
                     fabsf(xr[r].z - yb.z) + fabsf(xr[r].w - yb.w);
      }
    }
  };

  issue(xsA, ysA, 0);
  __syncthreads();  // vmcnt drained by barrier -> chunk 0 resident
  issue(xsB, ysB, 64);
  compute(xsA, ysA);
  __syncthreads();  // all reads of A done; B's loads drained
  issue(xsA, ysA, 128);
  compute(xsB, ysB);
  __syncthreads();
  issue(xsB, ysB, 192);
  compute(xsA, ysA);
  __syncthreads();
  compute(xsB, ysB);

  float kv[4][2];
#pragma unroll
  for (int r = 0; r < 4; ++r) {
    kv[r][0] = expf(-acc[r][0] * INV_EPS);
    kv[r][1] = expf(-acc[r][1] * INV_EPS);
  }
  const int gr0 = bi * 64 + ty * 4;
  const int gc0 = bj * 32 + c0;
#pragma unroll
  for (int r = 0; r < 4; ++r)
    *reinterpret_cast<float2*>(Km + (size_t)(gr0 + r) * N + gc0) =
        make_float2(kv[r][0], kv[r][1]);
  // KT via LDS transpose (reuse xsA = trans[32][64], XOR-swizzled granules).
  // Writes: 2 lanes/bank (free); reads: permuted float4s, conflict-free.
  float* trans = xsA;
  const int tsw = (tx >> 1) & 7;  // (c0>>2)&7 == (c1>>2)&7
#pragma unroll
  for (int r = 0; r < 4; ++r) {
    trans[c0 * 64 + ((ty ^ tsw) << 2) + r] = kv[r][0];
    trans[c1 * 64 + ((ty ^ tsw) << 2) + r] = kv[r][1];
  }
  __syncthreads();
#pragma unroll
  for (int it = 0; it < 2; ++it) {
    const int l = it * 256 + t;
    const int crow = l >> 4, cq = l & 15;  // crow: col of K (row of KT)
    const float4 val = *reinterpret_cast<const float4*>(
        &trans[crow * 64 + ((cq ^ ((crow >> 2) & 7)) << 2)]);
    *reinterpret_cast<float4*>(KTm + (size_t)(bj * 32 + crow) * N + bi * 64 +
                               cq * 4) = val;
  }
}

// ---- persistent Sinkhorn: tagged dataflow + off-path aggregator (R11) ----
__global__ __launch_bounds__(256, 1) void sinkhorn_coop(
    const float* __restrict__ Km, const float* __restrict__ KTm,
    uint64_t* __restrict__ U, uint64_t* __restrict__ V,
    uint64_t* __restrict__ DERR, uint64_t* __restrict__ PART,
    uint64_t* __restrict__ DONE, float* __restrict__ out) {
  const int b = blockIdx.x, t = threadIdx.x;
  const int lane = t & 63, w = t >> 6;

  if (b == 256) {  // ---- aggregator block (wave 0 only) ----
    if (w != 0) return;
    for (int it = 0; it < 9; ++it) {
      const uint32_t k = it + 1;
      float e = 0.f;
#pragma unroll
      for (int q = 0; q < 16; ++q) {
        const int idx = q * 64 + lane;
        uint64_t d;
        while ((uint32_t)((d = rload64(DERR + idx)) >> 32) != k)
          __builtin_amdgcn_s_sleep(1);
        e += __uint_as_float((uint32_t)d);
      }
      e = waveReduceSum(e);
      if (lane == 0)
        rstore64(DONE + it, ((uint64_t)k << 32) | (e < 0.1f ? 1u : 0u));
      if (__shfl(e, 0) < 0.1f) return;  // later DERR tags never arrive
    }
    return;
  }

  __shared__ float sB[N];
  __shared__ float sRed[4];
  __shared__ int sDone;
  const int i = b * 4 + w;
  const float* Krow = Km + (size_t)i * N;
  const float* Trow = KTm + (size_t)i * N;

  float ui = 0.f, vj = 0.f;
  int klast = 0;

  for (int it = 0; it < 10; ++it) {
    const uint32_t k = it + 1;
    // ---- stage b_j = exp(v^{k-1}_j/eps); k-1==0 -> ones ----
    if (it == 0) {
      *reinterpret_cast<float4*>(&sB[t * 4]) = make_float4(1.f, 1.f, 1.f, 1.f);
    } else {
      stage_exp(V + (size_t)((k - 1) & 1) * N, k - 1, sB, t);
    }
    __syncthreads();
    // ---- row pass: S = sum_j K_ij b_j ; u update; publish U and DERR ----
    {
      float s = 0.f;
#pragma unroll
      for (int q = 0; q < 4; ++q) {
        const int j4 = (q * 64 + lane) * 4;
        const float4 k4 = *reinterpret_cast<const float4*>(Krow + j4);
        s += k4.x * sB[j4] + k4.y * sB[j4 + 1] + k4.z * sB[j4 + 2] +
             k4.w * sB[j4 + 3];
      }
      s = waveReduceSum(s);
      const float un =
          EPS * (LOG_MU - logf(expf(ui * INV_EPS) * s + 1e-6f)) + ui;
      const float de = fabsf(un - ui);
      ui = un;
      if (lane == 0) {
        rstore64(U + (size_t)(k & 1) * N + i, packtag(k, ui));
        if (it < 9) rstore64(DERR + i, packtag(k, de));
      }
    }
    __syncthreads();  // all waves done reading sB before restage
    // ---- stage a_i = exp(u^k_i/eps) ----
    stage_exp(U + (size_t)(k & 1) * N, k, sB, t);
    __syncthreads();
    // ---- col pass: v update; iteration 10 fuses the loss ----
    if (it < 9) {
      float s = 0.f;
#pragma unroll
      for (int q = 0; q < 4; ++q) {
        const int i4 = (q * 64 + lane) * 4;
        const float4 k4 = *reinterpret_cast<const float4*>(Trow + i4);
        s += k4.x * sB[i4] + k4.y * sB[i4 + 1] + k4.z * sB[i4 + 2] +
             k4.w * sB[i4 + 3];
      }
      s = waveReduceSum(s);
      vj = EPS * (LOG_MU - logf(expf(vj * INV_EPS) * s + 1e-6f)) + vj;
      if (lane == 0) rstore64(V + (size_t)(k & 1) * N + i, packtag(k, vj));
      klast = (int)k;
      // ---- DONE poll (aggregator published it during our col pass) ----
      if (t == 0) {
        uint64_t d;
        while ((uint32_t)((d = rload64(DONE + it)) >> 32) != k)
          __builtin_amdgcn_s_sleep(1);
        sDone = (int)(d & 1);
      }
      __syncthreads();  // also guards sB restage of next iteration
      if (sDone) break;
    } else {
      // last col pass: s = sum KT*a ; sl = sum KT*a*C, C = -eps*ln(KT)
      float s = 0.f, sl = 0.f;
#pragma unroll
      for (int q = 0; q < 4; ++q) {
        const int i4 = (q * 64 + lane) * 4;
        const float4 k4 = *reinterpret_cast<const float4*>(Trow + i4);
        const float p0 = k4.x * sB[i4], p1 = k4.y * sB[i4 + 1],
                    p2 = k4.z * sB[i4 + 2], p3 = k4.w * sB[i4 + 3];
        s += p0 + p1 + p2 + p3;
        sl += p0 * logf(k4.x) + p1 * logf(k4.y) + p2 * logf(k4.z) +
              p3 * logf(k4.w);
      }
      s = waveReduceSum(s);
      sl = waveReduceSum(sl) * -EPS;
      vj = EPS * (LOG_MU - logf(expf(vj * INV_EPS) * s + 1e-6f)) + vj;
      if (lane == 0) rstore64(PART + i, packtag(1u, expf(vj * INV_EPS) * sl));
      klast = 10;
    }
  }
  // ---- early-exit loss path (statically unreachable for this input) ----
  if (klast < 10) {
    stage_exp(V + (size_t)(klast & 1) * N, (uint32_t)klast, sB, t);
    __syncthreads();
    float sl = 0.f;
#pragma unroll
    for (int q = 0; q < 4; ++q) {
      const int j4 = (q * 64 + lane) * 4;
      const float4 k4 = *reinterpret_cast<const float4*>(Krow + j4);
      sl += (k4.x * sB[j4]) * logf(k4.x) + (k4.y * sB[j4 + 1]) * logf(k4.y) +
            (k4.z * sB[j4 + 2]) * logf(k4.z) +
            (k4.w * sB[j4 + 3]) * logf(k4.w);
    }
    sl = waveReduceSum(sl) * -EPS;
    if (lane == 0) rstore64(PART + i, packtag(1u, expf(ui * INV_EPS) * sl));
  }
  // ---- final reduce: block 0 polls 1024 partials, fixed-order tree ----
  if (b == 0) {
    float acc = 0.f;
#pragma unroll
    for (int q = 0; q < 4; ++q) {
      const int idx = t * 4 + q;
      uint64_t d;
      while ((uint32_t)((d = rload64(PART + idx)) >> 32) != 1u)
        __builtin_amdgcn_s_sleep(1);
      acc += __uint_as_float((uint32_t)d);
    }
    acc = waveReduceSum(acc);
    if (lane == 0) sRed[w] = acc;
    __syncthreads();
    if (t == 0) out[0] = sRed[0] + sRed[1] + sRed[2] + sRed[3];
  }
}

extern "C" void kernel_launch(void* const* d_in, const int* in_sizes, int n_in,
                              void* d_out, int out_size, void* d_ws,
                              size_t ws_size, hipStream_t stream) {
  const float* x = (const float*)d_in[0];  // "output"
  const float* y = (const float*)d_in[1];  // "target"
  float* out = (float*)d_out;

  const size_t nn = (size_t)N * N;
  float* Km = (float*)d_ws;
  float* KTm = Km + nn;
  uint64_t* tags = (uint64_t*)(KTm + nn);
  uint64_t* U = tags;          // 2*N
  uint64_t* V = U + 2 * N;     // 2*N
  uint64_t* DERR = V + 2 * N;  // N
  uint64_t* PART = DERR + N;   // N
  uint64_t* DONE = PART + N;   // 16

  cmat_kernel<<<dim3(32, 16), 256, 0, stream>>>(x, y, Km, KTm, tags);
  sinkhorn_coop<<<257, 256, 0, stream>>>(Km, KTm, U, V, DERR, PART, DONE, out);
}

// Round 17
// 57.607 us; speedup vs baseline: 1.1461x; 1.0241x over previous
//
#include <hip/hip_runtime.h>
#include <stdint.h>

#define N 1024
#define DD 256
#define EPS 100.0f
#define INV_EPS 0.01f
#define LOG_MU -6.93147180559945f

__device__ __forceinline__ float waveReduceSum(float s) {
#pragma unroll
  for (int m = 1; m <= 32; m <<= 1) s += __shfl_xor(s, m);
  return s;
}

// Relaxed agent-scope 64-bit accesses (cache-bypassing, no cache maintenance).
__device__ __forceinline__ uint64_t rload64(const uint64_t* p) {
  return __hip_atomic_load(p, __ATOMIC_RELAXED, __HIP_MEMORY_SCOPE_AGENT);
}
__device__ __forceinline__ void rstore64(uint64_t* p, uint64_t x) {
  __hip_atomic_store(p, x, __ATOMIC_RELAXED, __HIP_MEMORY_SCOPE_AGENT);
}
__device__ __forceinline__ uint64_t packtag(uint32_t tag, float val) {
  return ((uint64_t)tag << 32) | (uint64_t)__float_as_uint(val);
}

// Poll 2 tagged words (thread t owns slots t*2, t*2+1), write exp(val/eps)
// into sB. All-or-nothing reload keeps both loads pipelined.
__device__ __forceinline__ void stage_exp2(const uint64_t* __restrict__ src,
                                           uint32_t want, float* sB, int t) {
  const int base = t * 2;
  for (;;) {
    const uint64_t a0 = rload64(src + base + 0);
    const uint64_t a1 = rload64(src + base + 1);
    if ((uint32_t)(a0 >> 32) == want && (uint32_t)(a1 >> 32) == want) {
      sB[base + 0] = expf(__uint_as_float((uint32_t)a0) * INV_EPS);
      sB[base + 1] = expf(__uint_as_float((uint32_t)a1) * INV_EPS);
      return;
    }
    __builtin_amdgcn_s_sleep(1);
  }
}

#define NTAGS 6160  // U(2048) V(2048) DERR(1024) PART(1024) DONE(16)

typedef __attribute__((address_space(3))) uint32_t lds_u32_t;
typedef __attribute__((address_space(1))) const uint32_t glb_u32_t;
__device__ __forceinline__ void gload_lds16(const float* g, float* l) {
  __builtin_amdgcn_global_load_lds((glb_u32_t*)g, (lds_u32_t*)l, 16, 0, 0);
}

// ---- cmat: K=exp(-|x-y|_1/eps) and KT; zeroes tag words each call ----
// R16-proven: 64x32 tile, grid (32,16)=512 blocks (2/CU), 4x2 acc,
// global_load_lds(16) + double-buffered LDS, pre-swizzled global source.
__global__ __launch_bounds__(256) void cmat_kernel(
    const float* __restrict__ x, const float* __restrict__ y,
    float* __restrict__ Km, float* __restrict__ KTm,
    uint64_t* __restrict__ tags) {
  __shared__ float xsA[64 * 64], xsB[64 * 64];  // 16 KB each
  __shared__ float ysA[32 * 64], ysB[32 * 64];  // 8 KB each
  const int t = threadIdx.x;
  const int bj = blockIdx.x;  // 32-col tile
  const int bi = blockIdx.y;  // 64-row tile
  if (bi == 0 && bj == 0) {   // coop runs strictly after in stream order
    for (int z = t; z < NTAGS; z += 256) tags[z] = 0;
  }
  const int tx = t & 15;
  const int ty = t >> 4;
  const int c0 = tx * 2, c1 = c0 + 1;
  const int xsw = (ty & 7) << 2;         // read swizzle: ((ty*4+r)>>2)&7 = ty
  const int ysw = ((tx >> 1) & 7) << 2;  // ((2tx)>>2)&7 == ((2tx+1)>>2)&7
  const float* xg = x + (size_t)(bi * 64) * DD;
  const float* yg = y + (size_t)(bj * 32) * DD;

  float acc[4][2] = {};

  auto issue = [&](float* xs, float* ys, int kc) {
#pragma unroll
    for (int q = 0; q < 4; ++q) {  // xs: 1024 slots (64 rows x 16 granules)
      const int s = q * 256 + t;
      const int row = s >> 4, c16 = s & 15;
      const int g16 = c16 ^ ((row >> 2) & 7);  // pre-swizzled source granule
      gload_lds16(xg + (size_t)row * DD + kc + g16 * 4, xs + s * 4);
    }
#pragma unroll
    for (int q = 0; q < 2; ++q) {  // ys: 512 slots (32 rows x 16 granules)
      const int s = q * 256 + t;
      const int row = s >> 4, c16 = s & 15;
      const int g16 = c16 ^ ((row >> 2) & 7);
      gload_lds16(yg + (size_t)row * DD + kc + g16 * 4, ys + s * 4);
    }
  };

  auto compute = [&](const float* xs, const float* ys) {
#pragma unroll 2
    for (int kk = 0; kk < 64; kk += 4) {
      float4 xr[4];
#pragma unroll
      for (int r = 0; r < 4; ++r)
        xr[r] = *reinterpret_cast<const float4*>(
            &xs[(ty * 4 + r) * 64 + (kk ^ xsw)]);
      const float4 ya =
          *reinterpret_cast<const float4*>(&ys[c0 * 64 + (kk ^ ysw)]);
      const float4 yb =
          *reinterpret_cast<const float4*>(&ys[c1 * 64 + (kk ^ ysw)]);
#pragma unroll
      for (int r = 0; r < 4; ++r) {
        acc[r][0] += fabsf(xr[r].x - ya.x) + fabsf(xr[r].y - ya.y) +
                     fabsf(xr[r].z - ya.z) + fabsf(xr[r].w - ya.w);
        acc[r][1] += fabsf(xr[r].x - yb.x) + fabsf(xr[r].y - yb.y) +
                     fabsf(xr[r].z - yb.z) + fabsf(xr[r].w - yb.w);
      }
    }
  };

  issue(xsA, ysA, 0);
  __syncthreads();  // vmcnt drained by barrier -> chunk 0 resident
  issue(xsB, ysB, 64);
  compute(xsA, ysA);
  __syncthreads();  // all reads of A done; B's loads drained
  issue(xsA, ysA, 128);
  compute(xsB, ysB);
  __syncthreads();
  issue(xsB, ysB, 192);
  compute(xsA, ysA);
  __syncthreads();
  compute(xsB, ysB);

  float kv[4][2];
#pragma unroll
  for (int r = 0; r < 4; ++r) {
    kv[r][0] = expf(-acc[r][0] * INV_EPS);
    kv[r][1] = expf(-acc[r][1] * INV_EPS);
  }
  const int gr0 = bi * 64 + ty * 4;
  const int gc0 = bj * 32 + c0;
#pragma unroll
  for (int r = 0; r < 4; ++r)
    *reinterpret_cast<float2*>(Km + (size_t)(gr0 + r) * N + gc0) =
        make_float2(kv[r][0], kv[r][1]);
  // KT via LDS transpose (reuse xsA = trans[32][64], XOR-swizzled granules).
  float* trans = xsA;
  const int tsw = (tx >> 1) & 7;  // (c0>>2)&7 == (c1>>2)&7
#pragma unroll
  for (int r = 0; r < 4; ++r) {
    trans[c0 * 64 + ((ty ^ tsw) << 2) + r] = kv[r][0];
    trans[c1 * 64 + ((ty ^ tsw) << 2) + r] = kv[r][1];
  }
  __syncthreads();
#pragma unroll
  for (int it = 0; it < 2; ++it) {
    const int l = it * 256 + t;
    const int crow = l >> 4, cq = l & 15;  // crow: col of K (row of KT)
    const float4 val = *reinterpret_cast<const float4*>(
        &trans[crow * 64 + ((cq ^ ((crow >> 2) & 7)) << 2)]);
    *reinterpret_cast<float4*>(KTm + (size_t)(bj * 32 + crow) * N + bi * 64 +
                               cq * 4) = val;
  }
}

// ---- persistent Sinkhorn: tagged dataflow + off-path aggregator ----
// 512-thread compute blocks: wave w (half = w>>2) computes the half-range
// [half*512, half*512+512) of row/col i = b*4 + (w&3); halves combined via
// LDS partials; waves 0-3 do the scalar update + publish. Halves per-wave
// matvec work and stage poll depth; 8 waves/CU hide L1/LDS latency. Hop
// structure, tags, aggregator, fused loss, early-exit semantics unchanged.
__global__ __launch_bounds__(512, 1) void sinkhorn_coop(
    const float* __restrict__ Km, const float* __restrict__ KTm,
    uint64_t* __restrict__ U, uint64_t* __restrict__ V,
    uint64_t* __restrict__ DERR, uint64_t* __restrict__ PART,
    uint64_t* __restrict__ DONE, float* __restrict__ out) {
  const int b = blockIdx.x, t = threadIdx.x;
  const int lane = t & 63, w = t >> 6;

  if (b == 256) {  // ---- aggregator block (wave 0 only) ----
    if (w != 0) return;
    for (int it = 0; it < 9; ++it) {
      const uint32_t k = it + 1;
      float e = 0.f;
#pragma unroll
      for (int q = 0; q < 16; ++q) {
        const int idx = q * 64 + lane;
        uint64_t d;
        while ((uint32_t)((d = rload64(DERR + idx)) >> 32) != k)
          __builtin_amdgcn_s_sleep(1);
        e += __uint_as_float((uint32_t)d);
      }
      e = waveReduceSum(e);
      if (lane == 0)
        rstore64(DONE + it, ((uint64_t)k << 32) | (e < 0.1f ? 1u : 0u));
      if (__shfl(e, 0) < 0.1f) return;  // later DERR tags never arrive
    }
    return;
  }

  __shared__ float sB[N];
  __shared__ float sPart[8];
  __shared__ float sPart2[8];
  __shared__ float sRed[8];
  __shared__ int sDone;
  const int rw = w & 3;     // which of the block's 4 rows/cols
  const int half = w >> 2;  // which 512-element half of the matvec
  const int i = b * 4 + rw;
  const float* Krow = Km + (size_t)i * N;
  const float* Trow = KTm + (size_t)i * N;

  float ui = 0.f, vj = 0.f;  // tracked by half==0 waves
  int klast = 0;

  for (int it = 0; it < 10; ++it) {
    const uint32_t k = it + 1;
    // ---- stage b_j = exp(v^{k-1}_j/eps); k-1==0 -> ones ----
    if (it == 0) {
      *reinterpret_cast<float2*>(&sB[t * 2]) = make_float2(1.f, 1.f);
    } else {
      stage_exp2(V + (size_t)((k - 1) & 1) * N, k - 1, sB, t);
    }
    __syncthreads();
    // ---- row pass (half-matvec per wave) ----
    {
      float s = 0.f;
#pragma unroll
      for (int q = 0; q < 2; ++q) {
        const int j4 = half * 512 + (q * 64 + lane) * 4;
        const float4 k4 = *reinterpret_cast<const float4*>(Krow + j4);
        const float4 b4 = *reinterpret_cast<const float4*>(&sB[j4]);
        s += k4.x * b4.x + k4.y * b4.y + k4.z * b4.z + k4.w * b4.w;
      }
      s = waveReduceSum(s);
      if (lane == 0) sPart[w] = s;
    }
    __syncthreads();  // partials ready; also: all sB reads done
    if (half == 0) {
      const float s = sPart[w] + sPart[w + 4];
      const float un =
          EPS * (LOG_MU - logf(expf(ui * INV_EPS) * s + 1e-6f)) + ui;
      const float de = fabsf(un - ui);
      ui = un;
      if (lane == 0) {
        rstore64(U + (size_t)(k & 1) * N + i, packtag(k, ui));
        if (it < 9) rstore64(DERR + i, packtag(k, de));
      }
    }
    // ---- stage a_i = exp(u^k_i/eps) (tag-synchronized, no barrier) ----
    stage_exp2(U + (size_t)(k & 1) * N, k, sB, t);
    __syncthreads();
    // ---- col pass (half-matvec per wave); iteration 10 fuses the loss ----
    if (it < 9) {
      float s = 0.f;
#pragma unroll
      for (int q = 0; q < 2; ++q) {
        const int i4 = half * 512 + (q * 64 + lane) * 4;
        const float4 k4 = *reinterpret_cast<const float4*>(Trow + i4);
        const float4 a4 = *reinterpret_cast<const float4*>(&sB[i4]);
        s += k4.x * a4.x + k4.y * a4.y + k4.z * a4.z + k4.w * a4.w;
      }
      s = waveReduceSum(s);
      if (lane == 0) sPart[w] = s;
      __syncthreads();
      if (half == 0) {
        const float s2 = sPart[w] + sPart[w + 4];
        vj = EPS * (LOG_MU - logf(expf(vj * INV_EPS) * s2 + 1e-6f)) + vj;
        if (lane == 0) rstore64(V + (size_t)(k & 1) * N + i, packtag(k, vj));
      }
      klast = (int)k;
      // ---- DONE poll (aggregator published it during our col pass) ----
      if (t == 0) {
        uint64_t d;
        while ((uint32_t)((d = rload64(DONE + it)) >> 32) != k)
          __builtin_amdgcn_s_sleep(1);
        sDone = (int)(d & 1);
      }
      __syncthreads();  // also guards sB restage of next iteration
      if (sDone) break;
    } else {
      // last col pass: s = sum KT*a ; sl = sum KT*a*C, C = -eps*ln(KT)
      float s = 0.f, sl = 0.f;
#pragma unroll
      for (int q = 0; q < 2; ++q) {
        const int i4 = half * 512 + (q * 64 + lane) * 4;
        const float4 k4 = *reinterpret_cast<const float4*>(Trow + i4);
        const float4 a4 = *reinterpret_cast<const float4*>(&sB[i4]);
        const float p0 = k4.x * a4.x, p1 = k4.y * a4.y, p2 = k4.z * a4.z,
                    p3 = k4.w * a4.w;
        s += p0 + p1 + p2 + p3;
        sl += p0 * logf(k4.x) + p1 * logf(k4.y) + p2 * logf(k4.z) +
              p3 * logf(k4.w);
      }
      s = waveReduceSum(s);
      sl = waveReduceSum(sl);
      if (lane == 0) {
        sPart[w] = s;
        sPart2[w] = sl;
      }
      __syncthreads();
      if (half == 0) {
        const float s2 = sPart[w] + sPart[w + 4];
        const float sl2 = (sPart2[w] + sPart2[w + 4]) * -EPS;
        vj = EPS * (LOG_MU - logf(expf(vj * INV_EPS) * s2 + 1e-6f)) + vj;
        if (lane == 0)
          rstore64(PART + i, packtag(1u, expf(vj * INV_EPS) * sl2));
      }
      klast = 10;
    }
  }
  __syncthreads();  // iteration partial reads done before sRed reuse below
  // ---- early-exit loss path (statically unreachable for this input) ----
  if (klast < 10) {
    stage_exp2(V + (size_t)(klast & 1) * N, (uint32_t)klast, sB, t);
    __syncthreads();
    if (half == 0) {
      float sl = 0.f;
#pragma unroll
      for (int q = 0; q < 4; ++q) {
        const int j4 = (q * 64 + lane) * 4;
        const float4 k4 = *reinterpret_cast<const float4*>(Krow + j4);
        sl += (k4.x * sB[j4]) * logf(k4.x) +
              (k4.y * sB[j4 + 1]) * logf(k4.y) +
              (k4.z * sB[j4 + 2]) * logf(k4.z) +
              (k4.w * sB[j4 + 3]) * logf(k4.w);
      }
      sl = waveReduceSum(sl) * -EPS;
      if (lane == 0) rstore64(PART + i, packtag(1u, expf(ui * INV_EPS) * sl));
    }
  }
  // ---- final reduce: block 0 polls 1024 partials (2 per thread) ----
  if (b == 0) {
    float acc = 0.f;
#pragma unroll
    for (int q = 0; q < 2; ++q) {
      const int idx = t * 2 + q;
      uint64_t d;
      while ((uint32_t)((d = rload64(PART + idx)) >> 32) != 1u)
        __builtin_amdgcn_s_sleep(1);
      acc += __uint_as_float((uint32_t)d);
    }
    acc = waveReduceSum(acc);
    if (lane == 0) sRed[w] = acc;
    __syncthreads();
    if (t == 0)
      out[0] = sRed[0] + sRed[1] + sRed[2] + sRed[3] + sRed[4] + sRed[5] +
               sRed[6] + sRed[7];
  }
}

extern "C" void kernel_launch(void* const* d_in, const int* in_sizes, int n_in,
                              void* d_out, int out_size, void* d_ws,
                              size_t ws_size, hipStream_t stream) {
  const float* x = (const float*)d_in[0];  // "output"
  const float* y = (const float*)d_in[1];  // "target"
  float* out = (float*)d_out;

  const size_t nn = (size_t)N * N;
  float* Km = (float*)d_ws;
  float* KTm = Km + nn;
  uint64_t* tags = (uint64_t*)(KTm + nn);
  uint64_t* U = tags;          // 2*N
  uint64_t* V = U + 2 * N;     // 2*N
  uint64_t* DERR = V + 2 * N;  // N
  uint64_t* PART = DERR + N;   // N
  uint64_t* DONE = PART + N;   // 16

  cmat_kernel<<<dim3(32, 16), 256, 0, stream>>>(x, y, Km, KTm, tags);
  sinkhorn_coop<<<257, 512, 0, stream>>>(Km, KTm, U, V, DERR, PART, DONE, out);
}